// Round 1
// baseline (3537.780 us; speedup 1.0000x reference)
//
#include <hip/hip_runtime.h>

// Problem: B=512, M=40, D=64. Three bilinear layers, 200 outputs each.
// out1[b,o,d] = relu(b1[o] + sum_{m,n<40}  x[b,m,d]*x[b,n,d] *w1[o,m*40+n])
// out2[b,o,d] = relu(b2[o] + sum_{m<40,n<100} x[b,m,d]*h1[b,n,d]*w2[o,m*100+n])
// out3[b,o,d] = relu(b3[o] + sum_{m<40,n<100} x[b,m,d]*h2[b,n,d]*w3[o,m*100+n])
// h1 = out1[:,0:100,:], h2 = out2[:,0:100,:]
// output (B,400): rows 0:100 = sum_d out1[:,100:200,:], 100:200 = sum_d out2[:,100:200,:],
//                 200:400 = sum_d out3
//
// One block per b, 512 threads = 8 waves. lane = d. Wave w owns outputs
// o in [25w, 25w+25). Weights are wave-uniform -> scalar loads via K$.

__global__ __launch_bounds__(512, 1)
void fused_bilinear_kernel(const float* __restrict__ x,
                           const float* __restrict__ w1, const float* __restrict__ b1,
                           const float* __restrict__ w2, const float* __restrict__ b2,
                           const float* __restrict__ w3, const float* __restrict__ b3,
                           float* __restrict__ out) {
    const int b   = blockIdx.x;
    const int tid = threadIdx.x;
    const int d   = tid & 63;
    const int wv  = tid >> 6;   // wave id 0..7

    __shared__ float xs[40][64];   // x[b, m, d]
    __shared__ float hs[100][64];  // hidden[n, d]

    // stage x[b]: 2560 floats, coalesced
    const float* xb = x + (size_t)b * 40 * 64;
    for (int i = tid; i < 40 * 64; i += 512) {
        ((float*)xs)[i] = xb[i];
    }
    __syncthreads();

    // per-lane copies of x (static-indexed -> registers)
    float xr[40];
    #pragma unroll
    for (int m = 0; m < 40; ++m) xr[m] = xs[m][d];

    float hr[100];

    const int o0 = __builtin_amdgcn_readfirstlane(wv * 25);

    // ---------------- layer 1 ----------------
    for (int oi = 0; oi < 25; ++oi) {
        const int o = o0 + oi;
        const float* __restrict__ wrow = w1 + (size_t)o * 1600;
        float s = b1[o];
        for (int m = 0; m < 40; ++m) {
            const float* __restrict__ wm = wrow + m * 40;
            float a0 = 0.f, a1 = 0.f, a2 = 0.f, a3 = 0.f;
            #pragma unroll
            for (int n = 0; n < 40; n += 4) {
                a0 = fmaf(wm[n + 0], xr[n + 0], a0);
                a1 = fmaf(wm[n + 1], xr[n + 1], a1);
                a2 = fmaf(wm[n + 2], xr[n + 2], a2);
                a3 = fmaf(wm[n + 3], xr[n + 3], a3);
            }
            const float sm = (a0 + a1) + (a2 + a3);
            s = fmaf(xs[m][d], sm, s);
        }
        s = fmaxf(s, 0.f);
        if (o < 100) {
            hs[o][d] = s;   // hidden h1
        } else {
            float r = s;    // direct: reduce over d
            #pragma unroll
            for (int off = 32; off > 0; off >>= 1) r += __shfl_xor(r, off, 64);
            if (d == 0) out[(size_t)b * 400 + (o - 100)] = r;
        }
    }
    __syncthreads();

    #pragma unroll
    for (int n = 0; n < 100; ++n) hr[n] = hs[n][d];
    __syncthreads();   // everyone has h1 in regs before hs is overwritten

    // ---------------- layer 2 ----------------
    for (int oi = 0; oi < 25; ++oi) {
        const int o = o0 + oi;
        const float* __restrict__ wrow = w2 + (size_t)o * 4000;
        float s = b2[o];
        for (int m = 0; m < 40; ++m) {
            const float* __restrict__ wm = wrow + m * 100;
            float a0 = 0.f, a1 = 0.f, a2 = 0.f, a3 = 0.f;
            #pragma unroll
            for (int n = 0; n < 100; n += 4) {
                a0 = fmaf(wm[n + 0], hr[n + 0], a0);
                a1 = fmaf(wm[n + 1], hr[n + 1], a1);
                a2 = fmaf(wm[n + 2], hr[n + 2], a2);
                a3 = fmaf(wm[n + 3], hr[n + 3], a3);
            }
            const float sm = (a0 + a1) + (a2 + a3);
            s = fmaf(xs[m][d], sm, s);
        }
        s = fmaxf(s, 0.f);
        if (o < 100) {
            hs[o][d] = s;   // hidden h2
        } else {
            float r = s;
            #pragma unroll
            for (int off = 32; off > 0; off >>= 1) r += __shfl_xor(r, off, 64);
            if (d == 0) out[(size_t)b * 400 + 100 + (o - 100)] = r;
        }
    }
    __syncthreads();

    #pragma unroll
    for (int n = 0; n < 100; ++n) hr[n] = hs[n][d];

    // ---------------- layer 3 ----------------
    for (int oi = 0; oi < 25; ++oi) {
        const int o = o0 + oi;
        const float* __restrict__ wrow = w3 + (size_t)o * 4000;
        float s = b3[o];
        for (int m = 0; m < 40; ++m) {
            const float* __restrict__ wm = wrow + m * 100;
            float a0 = 0.f, a1 = 0.f, a2 = 0.f, a3 = 0.f;
            #pragma unroll
            for (int n = 0; n < 100; n += 4) {
                a0 = fmaf(wm[n + 0], hr[n + 0], a0);
                a1 = fmaf(wm[n + 1], hr[n + 1], a1);
                a2 = fmaf(wm[n + 2], hr[n + 2], a2);
                a3 = fmaf(wm[n + 3], hr[n + 3], a3);
            }
            const float sm = (a0 + a1) + (a2 + a3);
            s = fmaf(xs[m][d], sm, s);
        }
        s = fmaxf(s, 0.f);
        float r = s;
        #pragma unroll
        for (int off = 32; off > 0; off >>= 1) r += __shfl_xor(r, off, 64);
        if (d == 0) out[(size_t)b * 400 + 200 + o] = r;
    }
}

extern "C" void kernel_launch(void* const* d_in, const int* in_sizes, int n_in,
                              void* d_out, int out_size, void* d_ws, size_t ws_size,
                              hipStream_t stream) {
    const float* x  = (const float*)d_in[0];
    const float* w1 = (const float*)d_in[1];
    const float* b1 = (const float*)d_in[2];
    const float* w2 = (const float*)d_in[3];
    const float* b2 = (const float*)d_in[4];
    const float* w3 = (const float*)d_in[5];
    const float* b3 = (const float*)d_in[6];
    float* out = (float*)d_out;

    fused_bilinear_kernel<<<dim3(512), dim3(512), 0, stream>>>(
        x, w1, b1, w2, b2, w3, b3, out);
}

// Round 2
// 245.390 us; speedup vs baseline: 14.4170x; 14.4170x over previous
//
#include <hip/hip_runtime.h>
#include <hip/hip_bf16.h>

// ============================================================================
// Problem: B=512, M=40, D=64. Three bilinear layers (200 outputs each).
//   layer l: out[o,d] = relu(bias[o] + sum_c W[o,c] * U[c,d]),
//            U[(m,n),d] = x[m,d] * h[n,d]   (h = x for l=1, else prev hidden)
//   h_next = out[0:100]; direct rows reduced over d into out[b, 400].
//
// MFMA formulation: per b, per layer: C[200,64] = W[200,K] x U[K,64] (bf16).
//   K = 1600 / 4000 / 4000. Block = 2 b's (N=128). M padded to 256 rows
//   (prepass zero-pads W in d_ws). 8 waves = 4(m-groups) x 2(b/n-groups),
//   each wave: 4x4 block of 16x16x32 bf16 MFMAs (A from global/L1, B=U from
//   LDS, built on the fly, double-buffered, 1 barrier/kstep).
// ============================================================================

typedef float f32x4 __attribute__((ext_vector_type(4)));
typedef short bf16x8 __attribute__((ext_vector_type(8)));

#define XS_PAD 42     // x rows: 84B stride -> 21 dwords, gcd(21,32)=1 (<=2-way)
#define HS_PAD 102    // h rows: 204B stride -> 51 dwords, gcd(51,32)=1
// U rows: 17 uints = 68B -> 17 dwords, gcd(17,32)=1; frag read as 4x b32 -> 2-way

struct LDSState {
    __hip_bfloat16 xs[2][64][XS_PAD];      // [bb][d][m]
    __hip_bfloat16 hs[2][2][64][HS_PAD];   // [pp][bb][d][n]
    unsigned int   U[2][2][64][17];        // [buf][bb][d][k-pair] (34 bf16/row)
};

__device__ __forceinline__ float bflo(unsigned int u) {
    unsigned int v = u << 16;
    return __builtin_bit_cast(float, v);
}
__device__ __forceinline__ float bfhi(unsigned int u) {
    unsigned int v = u & 0xffff0000u;
    return __builtin_bit_cast(float, v);
}
__device__ __forceinline__ unsigned int pk_bf16(float a, float b) {
    unsigned int r;
    asm("v_cvt_pk_bf16_f32 %0, %1, %2" : "=v"(r) : "v"(a), "v"(b));
    return r;
}

// ---------------------------------------------------------------------------
// One layer: K-loop GEMM + epilogue (bias, relu, hidden store, direct rowsum)
// ---------------------------------------------------------------------------
template<int DIV, int KTOT, int HASH, int ROWLO, int ROWOFF>
__device__ __forceinline__ void layer_pass(
    LDSState* L, const bf16x8* __restrict__ wp8, const float* __restrict__ bias,
    const __hip_bfloat16* h0, const __hip_bfloat16* h1, int hstride,
    int dstpp, float* outb0, float* outb1, int tid)
{
    const int lane = tid & 63;
    const int wv   = tid >> 6;   // 0..7
    const int wm   = wv >> 1;    // 0..3 (m-group)
    const int wn   = wv & 1;     // 0..1 (b/n-group)
    const int q    = lane >> 4;  // 0..3
    const int lr   = lane & 15;
    const int d    = lane;

    f32x4 acc[4][4];
    #pragma unroll
    for (int mi = 0; mi < 4; ++mi)
        #pragma unroll
        for (int nj = 0; nj < 4; ++nj)
            acc[mi][nj] = {0.f, 0.f, 0.f, 0.f};

    const int K8 = KTOT / 8;
    int rowbase[4];
    #pragma unroll
    for (int mi = 0; mi < 4; ++mi)
        rowbase[mi] = (16 * (4 * wm + mi) + lr) * K8 + q;

    // build U slab for kstep s into buffer buf (wave wv builds k-local 4*wv..+3)
    auto build = [&](int s, int buf) {
        const int c0 = s * 32 + 4 * wv;
        const int m  = c0 / DIV;          // x index
        const int n0 = c0 % DIV;          // h index (even, pairs never straddle)
        #pragma unroll
        for (int bb = 0; bb < 2; ++bb) {
            const __hip_bfloat16* hb = bb ? h1 : h0;
            unsigned short xu = *(const unsigned short*)&L->xs[bb][d][m];
            float xf = bflo((unsigned int)xu);
            unsigned int h01 = *(const unsigned int*)(hb + (size_t)d * hstride + n0);
            unsigned int h23 = *(const unsigned int*)(hb + (size_t)d * hstride + n0 + 2);
            unsigned int p0 = pk_bf16(xf * bflo(h01), xf * bfhi(h01));
            unsigned int p1 = pk_bf16(xf * bflo(h23), xf * bfhi(h23));
            L->U[buf][bb][d][2 * wv]     = p0;
            L->U[buf][bb][d][2 * wv + 1] = p1;
        }
    };

    const int nk = KTOT / 32;
    bf16x8 aC[4], aN[4];
    #pragma unroll
    for (int mi = 0; mi < 4; ++mi) aC[mi] = wp8[rowbase[mi]];   // s=0 A-frags
    build(0, 0);
    __syncthreads();

    for (int s = 0; s < nk; ++s) {
        const int buf = s & 1;
        if (s + 1 < nk) {
            // issue next A-frag loads early so they drain before the barrier
            #pragma unroll
            for (int mi = 0; mi < 4; ++mi) aN[mi] = wp8[rowbase[mi] + (s + 1) * 4];
            build(s + 1, buf ^ 1);
        }
        union { unsigned int u[4]; bf16x8 v; } bf[4];
        #pragma unroll
        for (int nj = 0; nj < 4; ++nj) {
            const int dl = 16 * nj + lr;
            #pragma unroll
            for (int r = 0; r < 4; ++r)
                bf[nj].u[r] = L->U[buf][wn][dl][4 * q + r];
        }
        #pragma unroll
        for (int mi = 0; mi < 4; ++mi)
            #pragma unroll
            for (int nj = 0; nj < 4; ++nj)
                acc[mi][nj] = __builtin_amdgcn_mfma_f32_16x16x32_bf16(
                    aC[mi], bf[nj].v, acc[mi][nj], 0, 0, 0);
        #pragma unroll
        for (int mi = 0; mi < 4; ++mi) aC[mi] = aN[mi];
        __syncthreads();
    }

    // epilogue: C/D layout (m89-verified): row = 4*q + reg, col(d) = lr
    float* outp = wn ? outb1 : outb0;
    #pragma unroll
    for (int mi = 0; mi < 4; ++mi) {
        const int mt = 4 * wm + mi;
        #pragma unroll
        for (int reg = 0; reg < 4; ++reg) {
            const int o = 16 * mt + 4 * q + reg;
            if (o < 200) {
                const float bs = bias[o];
                float r0 = fmaxf(acc[mi][0][reg] + bs, 0.f);
                float r1 = fmaxf(acc[mi][1][reg] + bs, 0.f);
                float r2 = fmaxf(acc[mi][2][reg] + bs, 0.f);
                float r3 = fmaxf(acc[mi][3][reg] + bs, 0.f);
                if (HASH && o < 100) {
                    L->hs[dstpp][wn][ 0 + lr][o] = __float2bfloat16(r0);
                    L->hs[dstpp][wn][16 + lr][o] = __float2bfloat16(r1);
                    L->hs[dstpp][wn][32 + lr][o] = __float2bfloat16(r2);
                    L->hs[dstpp][wn][48 + lr][o] = __float2bfloat16(r3);
                }
                if (o >= ROWLO) {
                    float sv = (r0 + r1) + (r2 + r3);
                    sv += __shfl_xor(sv, 1, 64);
                    sv += __shfl_xor(sv, 2, 64);
                    sv += __shfl_xor(sv, 4, 64);
                    sv += __shfl_xor(sv, 8, 64);
                    if (lr == 0) outp[ROWOFF + (o - ROWLO)] = sv;
                }
            }
        }
    }
    __syncthreads();
}

__global__ __launch_bounds__(512, 2)
void fused_mfma(const float* __restrict__ x,
                const __hip_bfloat16* __restrict__ wp,
                const float* __restrict__ b1, const float* __restrict__ b2,
                const float* __restrict__ b3, float* __restrict__ out) {
    __shared__ LDSState L;
    const int tid = threadIdx.x;
    const int bi  = blockIdx.x;

    // stage x (2 b's), fp32 -> bf16, transposed to [d][m]
    for (int i = tid; i < 5120; i += 512) {
        int bb = (i >= 2560) ? 1 : 0;
        int r  = i - bb * 2560;
        float v = x[(size_t)(2 * bi + bb) * 2560 + r];
        L.xs[bb][r & 63][r >> 6] = __float2bfloat16(v);
    }
    __syncthreads();

    float* outb0 = out + (size_t)(2 * bi + 0) * 400;
    float* outb1 = out + (size_t)(2 * bi + 1) * 400;

    const bf16x8* w1p = (const bf16x8*)(wp);
    const bf16x8* w2p = (const bf16x8*)(wp + 409600);
    const bf16x8* w3p = (const bf16x8*)(wp + 1433600);

    layer_pass< 40, 1600, 1, 100,   0>(&L, w1p, b1, &L.xs[0][0][0], &L.xs[1][0][0],
                                       XS_PAD, 0, outb0, outb1, tid);
    layer_pass<100, 4000, 1, 100, 100>(&L, w2p, b2, &L.hs[0][0][0][0], &L.hs[0][1][0][0],
                                       HS_PAD, 1, outb0, outb1, tid);
    layer_pass<100, 4000, 0,   0, 200>(&L, w3p, b3, &L.hs[1][0][0][0], &L.hs[1][1][0][0],
                                       HS_PAD, 0, outb0, outb1, tid);
}

// ---------------------------------------------------------------------------
// Prepass: W fp32 -> bf16, rows padded 200 -> 256 with zeros, into d_ws.
// Layout: [W1p 256x1600][W2p 256x4000][W3p 256x4000] (element offsets below).
// ---------------------------------------------------------------------------
__global__ void convert_w(const float* __restrict__ w1, const float* __restrict__ w2,
                          const float* __restrict__ w3, __hip_bfloat16* __restrict__ wp) {
    int c = blockIdx.x * 256 + threadIdx.x;   // 8-element chunk id
    if (c >= 307200) return;
    const float* src; __hip_bfloat16* dst; int K; int base;
    if (c < 51200)       { src = w1; dst = wp;           K = 1600; base = c; }
    else if (c < 179200) { src = w2; dst = wp +  409600; K = 4000; base = c - 51200; }
    else                 { src = w3; dst = wp + 1433600; K = 4000; base = c - 179200; }
    int el  = base * 8;
    int row = el / K;
    int k   = el - row * K;
    unsigned int o[4];
    if (row < 200) {
        const float* p = src + (size_t)row * K + k;
        #pragma unroll
        for (int j = 0; j < 4; ++j) {
            __hip_bfloat16 lo = __float2bfloat16(p[2 * j]);
            __hip_bfloat16 hi = __float2bfloat16(p[2 * j + 1]);
            o[j] = (unsigned int)__builtin_bit_cast(unsigned short, lo)
                 | ((unsigned int)__builtin_bit_cast(unsigned short, hi) << 16);
        }
    } else {
        #pragma unroll
        for (int j = 0; j < 4; ++j) o[j] = 0u;
    }
    uint4* dp = (uint4*)(dst + (size_t)row * K + k);
    uint4 v; v.x = o[0]; v.y = o[1]; v.z = o[2]; v.w = o[3];
    *dp = v;
}

// ---------------------------------------------------------------------------
// Fallback (round-1 fp32 kernel) in case ws_size is too small for packed W.
// ---------------------------------------------------------------------------
__global__ __launch_bounds__(512, 1)
void fused_bilinear_kernel(const float* __restrict__ x,
                           const float* __restrict__ w1, const float* __restrict__ b1,
                           const float* __restrict__ w2, const float* __restrict__ b2,
                           const float* __restrict__ w3, const float* __restrict__ b3,
                           float* __restrict__ out) {
    const int b   = blockIdx.x;
    const int tid = threadIdx.x;
    const int d   = tid & 63;
    const int wv  = tid >> 6;

    __shared__ float xs[40][64];
    __shared__ float hs[100][64];

    const float* xb = x + (size_t)b * 40 * 64;
    for (int i = tid; i < 40 * 64; i += 512) ((float*)xs)[i] = xb[i];
    __syncthreads();

    float xr[40];
    #pragma unroll
    for (int m = 0; m < 40; ++m) xr[m] = xs[m][d];
    float hr[100];
    const int o0 = __builtin_amdgcn_readfirstlane(wv * 25);

    for (int oi = 0; oi < 25; ++oi) {
        const int o = o0 + oi;
        const float* __restrict__ wrow = w1 + (size_t)o * 1600;
        float s = b1[o];
        for (int m = 0; m < 40; ++m) {
            const float* __restrict__ wm = wrow + m * 40;
            float a0 = 0.f, a1 = 0.f, a2 = 0.f, a3 = 0.f;
            #pragma unroll
            for (int n = 0; n < 40; n += 4) {
                a0 = fmaf(wm[n + 0], xr[n + 0], a0);
                a1 = fmaf(wm[n + 1], xr[n + 1], a1);
                a2 = fmaf(wm[n + 2], xr[n + 2], a2);
                a3 = fmaf(wm[n + 3], xr[n + 3], a3);
            }
            s = fmaf(xs[m][d], (a0 + a1) + (a2 + a3), s);
        }
        s = fmaxf(s, 0.f);
        if (o < 100) hs[o][d] = s;
        else {
            float r = s;
            #pragma unroll
            for (int off = 32; off > 0; off >>= 1) r += __shfl_xor(r, off, 64);
            if (d == 0) out[(size_t)b * 400 + (o - 100)] = r;
        }
    }
    __syncthreads();
    #pragma unroll
    for (int n = 0; n < 100; ++n) hr[n] = hs[n][d];
    __syncthreads();

    for (int oi = 0; oi < 25; ++oi) {
        const int o = o0 + oi;
        const float* __restrict__ wrow = w2 + (size_t)o * 4000;
        float s = b2[o];
        for (int m = 0; m < 40; ++m) {
            const float* __restrict__ wm = wrow + m * 100;
            float a0 = 0.f, a1 = 0.f, a2 = 0.f, a3 = 0.f;
            #pragma unroll
            for (int n = 0; n < 100; n += 4) {
                a0 = fmaf(wm[n + 0], hr[n + 0], a0);
                a1 = fmaf(wm[n + 1], hr[n + 1], a1);
                a2 = fmaf(wm[n + 2], hr[n + 2], a2);
                a3 = fmaf(wm[n + 3], hr[n + 3], a3);
            }
            s = fmaf(xs[m][d], (a0 + a1) + (a2 + a3), s);
        }
        s = fmaxf(s, 0.f);
        if (o < 100) hs[o][d] = s;
        else {
            float r = s;
            #pragma unroll
            for (int off = 32; off > 0; off >>= 1) r += __shfl_xor(r, off, 64);
            if (d == 0) out[(size_t)b * 400 + 100 + (o - 100)] = r;
        }
    }
    __syncthreads();
    #pragma unroll
    for (int n = 0; n < 100; ++n) hr[n] = hs[n][d];

    for (int oi = 0; oi < 25; ++oi) {
        const int o = o0 + oi;
        const float* __restrict__ wrow = w3 + (size_t)o * 4000;
        float s = b3[o];
        for (int m = 0; m < 40; ++m) {
            const float* __restrict__ wm = wrow + m * 100;
            float a0 = 0.f, a1 = 0.f, a2 = 0.f, a3 = 0.f;
            #pragma unroll
            for (int n = 0; n < 100; n += 4) {
                a0 = fmaf(wm[n + 0], hr[n + 0], a0);
                a1 = fmaf(wm[n + 1], hr[n + 1], a1);
                a2 = fmaf(wm[n + 2], hr[n + 2], a2);
                a3 = fmaf(wm[n + 3], hr[n + 3], a3);
            }
            s = fmaf(xs[m][d], (a0 + a1) + (a2 + a3), s);
        }
        s = fmaxf(s, 0.f);
        float r = s;
        #pragma unroll
        for (int off = 32; off > 0; off >>= 1) r += __shfl_xor(r, off, 64);
        if (d == 0) out[(size_t)b * 400 + 200 + o] = r;
    }
}

extern "C" void kernel_launch(void* const* d_in, const int* in_sizes, int n_in,
                              void* d_out, int out_size, void* d_ws, size_t ws_size,
                              hipStream_t stream) {
    const float* x  = (const float*)d_in[0];
    const float* w1 = (const float*)d_in[1];
    const float* b1 = (const float*)d_in[2];
    const float* w2 = (const float*)d_in[3];
    const float* b2 = (const float*)d_in[4];
    const float* w3 = (const float*)d_in[5];
    const float* b3 = (const float*)d_in[6];
    float* out = (float*)d_out;

    if (ws_size >= 4915200) {
        __hip_bfloat16* wp = (__hip_bfloat16*)d_ws;
        convert_w<<<dim3(1200), dim3(256), 0, stream>>>(w1, w2, w3, wp);
        fused_mfma<<<dim3(256), dim3(512), 0, stream>>>(x, wp, b1, b2, b3, out);
    } else {
        fused_bilinear_kernel<<<dim3(512), dim3(512), 0, stream>>>(
            x, w1, b1, w2, b2, w3, b3, out);
    }
}

// Round 3
// 235.809 us; speedup vs baseline: 15.0027x; 1.0406x over previous
//
#include <hip/hip_runtime.h>
#include <hip/hip_bf16.h>

// ============================================================================
// B=512, M=40, D=64. Three bilinear layers (200 outputs each):
//   out[o,d] = relu(bias[o] + sum_c W[o,c]*U[c,d]), U[(m,n),d] = x[m,d]*h[n,d]
// Per b: GEMM C[208,64] = W[208,K] x U[K,64] in bf16, K = 1600/4000/4000.
// Block = 2 b's (N=128), grid 256 (1/CU). 8 waves = 4(m)x2(b).
// M = 13 tiles of 16 rows, assigned mt = 4*mi + wm (wave-uniform validity).
// W repacked by prepass into FRAG-CONTIGUOUS layout: for (mt,s), 64 lanes'
// bf16x8 stored contiguously (1KB) -> each A-frag load is one coalesced 1KB.
// U built on the fly into 4 LDS slabs (2-kstep phases, 1 barrier/2 ksteps).
// ============================================================================

typedef float f32x4 __attribute__((ext_vector_type(4)));
typedef short bf16x8 __attribute__((ext_vector_type(8)));
typedef unsigned int uint;

#define NTILES 13
#define XS_STR 42     // bf16 stride: 21 dwords, odd -> 2-way max
#define HS_STR 102    // 51 dwords, odd -> 2-way max
#define U_STR  19     // dwords; 19*lr+4q mod 32: max 3-way, mostly 2-way

struct LDSState {
    __hip_bfloat16 xs[2][64][XS_STR];     // [bb][d][m]
    __hip_bfloat16 hs[2][2][64][HS_STR];  // [pp][bb][d][n]
    uint U[4][2][64][U_STR];              // [kstep&3][bb][d][k-pair]
};

static __device__ __forceinline__ float bflo(uint u) {
    uint v = u << 16; return __builtin_bit_cast(float, v);
}
static __device__ __forceinline__ float bfhi(uint u) {
    uint v = u & 0xffff0000u; return __builtin_bit_cast(float, v);
}
static __device__ __forceinline__ uint pk_bf16(float a, float b) {
    uint r; asm("v_cvt_pk_bf16_f32 %0, %1, %2" : "=v"(r) : "v"(a), "v"(b));
    return r;
}

template<int DIV, int KTOT, int HASH, int ROWLO, int ROWOFF>
__device__ __forceinline__ void layer_pass(
    LDSState* L, const bf16x8* __restrict__ wpk, const float* __restrict__ bias,
    const __hip_bfloat16* __restrict__ h0, const __hip_bfloat16* __restrict__ h1,
    int hstride, int dstpp, float* outb0, float* outb1, int tid)
{
    const int lane = tid & 63;
    const int wv = tid >> 6, wm = wv >> 1, wn = wv & 1;
    const int q = lane >> 4, lr = lane & 15, d = lane;
    const int NS = KTOT / 32, nk = NS;

    bool mvalid[4];
    const bf16x8* pA[4];
    #pragma unroll
    for (int mi = 0; mi < 4; ++mi) {
        const int mt = 4 * mi + wm;
        mvalid[mi] = (mt < NTILES);
        pA[mi] = wpk + ((size_t)mt * NS * 64 + lane);
    }

    f32x4 acc[4][4];
    #pragma unroll
    for (int mi = 0; mi < 4; ++mi)
        #pragma unroll
        for (int nj = 0; nj < 4; ++nj)
            acc[mi][nj] = {0.f, 0.f, 0.f, 0.f};

    // build U slab for kstep k (wave wv builds k-local 4wv..4wv+3)
    auto build = [&](int k) {
        if (k >= nk) return;
        const int c0 = k * 32 + 4 * wv;
        const int m  = c0 / DIV;
        const int n0 = c0 % DIV;          // multiple of 4, never straddles row
        #pragma unroll
        for (int bb = 0; bb < 2; ++bb) {
            const __hip_bfloat16* hb = bb ? h1 : h0;
            float xf = __bfloat162float(L->xs[bb][d][m]);
            uint h01 = *(const uint*)(hb + (size_t)d * hstride + n0);
            uint h23 = *(const uint*)(hb + (size_t)d * hstride + n0 + 2);
            L->U[k & 3][bb][d][2 * wv]     = pk_bf16(xf * bflo(h01), xf * bfhi(h01));
            L->U[k & 3][bb][d][2 * wv + 1] = pk_bf16(xf * bflo(h23), xf * bfhi(h23));
        }
    };

    // one kstep of MFMAs against slab s&3
    auto consume = [&](int s, bf16x8* a) {
        const uint* ub = &L->U[s & 3][wn][0][0];
        bf16x8 bv[4];
        #pragma unroll
        for (int nj = 0; nj < 4; ++nj) {
            union { uint u[4]; bf16x8 v; } t;
            const int off = U_STR * (16 * nj + lr) + 4 * q;
            #pragma unroll
            for (int r = 0; r < 4; ++r) t.u[r] = ub[off + r];
            bv[nj] = t.v;
        }
        __builtin_amdgcn_s_setprio(1);
        #pragma unroll
        for (int mi = 0; mi < 4; ++mi) {
            if (!mvalid[mi]) continue;     // wave-uniform
            #pragma unroll
            for (int nj = 0; nj < 4; ++nj)
                acc[mi][nj] = __builtin_amdgcn_mfma_f32_16x16x32_bf16(
                    a[mi], bv[nj], acc[mi][nj], 0, 0, 0);
        }
        __builtin_amdgcn_s_setprio(0);
    };

    bf16x8 aC[4], aC2[4], aN[4], aN2[4];
    #pragma unroll
    for (int mi = 0; mi < 4; ++mi) if (mvalid[mi]) {
        aC[mi]  = pA[mi][0];
        aC2[mi] = pA[mi][64];
    }
    build(0); build(1);
    __syncthreads();

    for (int s = 0; s < nk; s += 2) {
        // issue-early: next phase's A-frags (full phase of latency cover)
        if (s + 2 < nk) {
            #pragma unroll
            for (int mi = 0; mi < 4; ++mi) if (mvalid[mi]) aN[mi] = pA[mi][(s + 2) * 64];
        }
        if (s + 3 < nk) {
            #pragma unroll
            for (int mi = 0; mi < 4; ++mi) if (mvalid[mi]) aN2[mi] = pA[mi][(s + 3) * 64];
        }
        // build next phase's U slabs (write slabs (s+2)&3, (s+3)&3; readers of
        // those slabs are past the previous barrier -> safe)
        build(s + 2); build(s + 3);
        // compute this phase
        consume(s, aC);
        if (s + 1 < nk) consume(s + 1, aC2);
        __syncthreads();
        #pragma unroll
        for (int mi = 0; mi < 4; ++mi) { aC[mi] = aN[mi]; aC2[mi] = aN2[mi]; }
    }

    // epilogue: C/D layout row = 4q+reg, col = lr (m89-verified)
    float* outp = wn ? outb1 : outb0;
    #pragma unroll
    for (int mi = 0; mi < 4; ++mi) {
        if (!mvalid[mi]) continue;
        const int mt = 4 * mi + wm;
        #pragma unroll
        for (int reg = 0; reg < 4; ++reg) {
            const int o = 16 * mt + 4 * q + reg;
            if (o < 200) {
                const float bs = bias[o];
                float r0 = fmaxf(acc[mi][0][reg] + bs, 0.f);
                float r1 = fmaxf(acc[mi][1][reg] + bs, 0.f);
                float r2 = fmaxf(acc[mi][2][reg] + bs, 0.f);
                float r3 = fmaxf(acc[mi][3][reg] + bs, 0.f);
                if (HASH && o < 100) {
                    L->hs[dstpp][wn][ 0 + lr][o] = __float2bfloat16(r0);
                    L->hs[dstpp][wn][16 + lr][o] = __float2bfloat16(r1);
                    L->hs[dstpp][wn][32 + lr][o] = __float2bfloat16(r2);
                    L->hs[dstpp][wn][48 + lr][o] = __float2bfloat16(r3);
                }
                if (o >= ROWLO) {
                    float sv = (r0 + r1) + (r2 + r3);
                    sv += __shfl_xor(sv, 1, 64);
                    sv += __shfl_xor(sv, 2, 64);
                    sv += __shfl_xor(sv, 4, 64);
                    sv += __shfl_xor(sv, 8, 64);
                    if (lr == 0) outp[ROWOFF + (o - ROWLO)] = sv;
                }
            }
        }
    }
    __syncthreads();
}

__global__ __launch_bounds__(512, 2)
void fused_mfma(const float* __restrict__ x,
                const bf16x8* __restrict__ wpk,
                const float* __restrict__ b1, const float* __restrict__ b2,
                const float* __restrict__ b3, float* __restrict__ out) {
    __shared__ LDSState L;
    const int tid = threadIdx.x;
    const int bi  = blockIdx.x;

    // stage x (2 b's), fp32 -> bf16, transposed to [d][m]
    for (int i = tid; i < 5120; i += 512) {
        int bb = (i >= 2560) ? 1 : 0;
        int r  = i - bb * 2560;
        float v = x[(size_t)(2 * bi + bb) * 2560 + r];
        L.xs[bb][r & 63][r >> 6] = __float2bfloat16(v);
    }
    __syncthreads();

    float* outb0 = out + (size_t)(2 * bi + 0) * 400;
    float* outb1 = out + (size_t)(2 * bi + 1) * 400;

    const bf16x8* w1p = wpk;             // 13*50*64  = 41600 frags
    const bf16x8* w2p = wpk + 41600;     // 13*125*64 = 104000
    const bf16x8* w3p = wpk + 145600;

    layer_pass< 40, 1600, 1, 100,   0>(&L, w1p, b1, &L.xs[0][0][0], &L.xs[1][0][0],
                                       XS_STR, 0, outb0, outb1, tid);
    layer_pass<100, 4000, 1, 100, 100>(&L, w2p, b2, &L.hs[0][0][0][0], &L.hs[0][1][0][0],
                                       HS_STR, 1, outb0, outb1, tid);
    layer_pass<100, 4000, 0,   0, 200>(&L, w3p, b3, &L.hs[1][0][0][0], &L.hs[1][1][0][0],
                                       HS_STR, 0, outb0, outb1, tid);
}

// ---------------------------------------------------------------------------
// Prepass: repack W fp32 -> bf16 frag-contiguous. Element c = one lane's
// bf16x8: c = layerbase + (mt*NS + s)*64 + lane, holding
// W[16*mt + (lane&15), 32*s + 8*(lane>>4) .. +8]  (rows >= 200 zero).
// ---------------------------------------------------------------------------
__global__ void convert_pack(const float* __restrict__ w1, const float* __restrict__ w2,
                             const float* __restrict__ w3, uint4* __restrict__ outp) {
    int c = blockIdx.x * 256 + threadIdx.x;
    if (c >= 249600) return;
    const float* src; int K, base;
    if (c < 41600)       { src = w1; K = 1600; base = c; }
    else if (c < 145600) { src = w2; K = 4000; base = c - 41600; }
    else                 { src = w3; K = 4000; base = c - 145600; }
    const int NS   = K / 32;
    const int lane = base & 63;
    const int t    = base >> 6;        // mt*NS + s
    const int mt   = t / NS;
    const int s    = t - mt * NS;
    const int row  = 16 * mt + (lane & 15);
    const int k0   = 32 * s + 8 * (lane >> 4);
    uint o[4];
    if (row < 200) {
        const float* p = src + (size_t)row * K + k0;
        #pragma unroll
        for (int j = 0; j < 4; ++j) {
            __hip_bfloat16 lo = __float2bfloat16(p[2 * j]);
            __hip_bfloat16 hi = __float2bfloat16(p[2 * j + 1]);
            o[j] = (uint)__builtin_bit_cast(unsigned short, lo)
                 | ((uint)__builtin_bit_cast(unsigned short, hi) << 16);
        }
    } else {
        #pragma unroll
        for (int j = 0; j < 4; ++j) o[j] = 0u;
    }
    uint4 v; v.x = o[0]; v.y = o[1]; v.z = o[2]; v.w = o[3];
    outp[c] = v;
}

// ---------------------------------------------------------------------------
// Fallback (round-1 fp32 kernel) if ws too small.
// ---------------------------------------------------------------------------
__global__ __launch_bounds__(512, 1)
void fused_bilinear_kernel(const float* __restrict__ x,
                           const float* __restrict__ w1, const float* __restrict__ b1,
                           const float* __restrict__ w2, const float* __restrict__ b2,
                           const float* __restrict__ w3, const float* __restrict__ b3,
                           float* __restrict__ out) {
    const int b   = blockIdx.x;
    const int tid = threadIdx.x;
    const int d   = tid & 63;
    const int wv  = tid >> 6;

    __shared__ float xs[40][64];
    __shared__ float hs[100][64];

    const float* xb = x + (size_t)b * 40 * 64;
    for (int i = tid; i < 40 * 64; i += 512) ((float*)xs)[i] = xb[i];
    __syncthreads();

    float xr[40];
    #pragma unroll
    for (int m = 0; m < 40; ++m) xr[m] = xs[m][d];
    float hr[100];
    const int o0 = __builtin_amdgcn_readfirstlane(wv * 25);

    for (int oi = 0; oi < 25; ++oi) {
        const int o = o0 + oi;
        const float* __restrict__ wrow = w1 + (size_t)o * 1600;
        float s = b1[o];
        for (int m = 0; m < 40; ++m) {
            const float* __restrict__ wm = wrow + m * 40;
            float a0 = 0.f, a1 = 0.f, a2 = 0.f, a3 = 0.f;
            #pragma unroll
            for (int n = 0; n < 40; n += 4) {
                a0 = fmaf(wm[n + 0], xr[n + 0], a0);
                a1 = fmaf(wm[n + 1], xr[n + 1], a1);
                a2 = fmaf(wm[n + 2], xr[n + 2], a2);
                a3 = fmaf(wm[n + 3], xr[n + 3], a3);
            }
            s = fmaf(xs[m][d], (a0 + a1) + (a2 + a3), s);
        }
        s = fmaxf(s, 0.f);
        if (o < 100) hs[o][d] = s;
        else {
            float r = s;
            #pragma unroll
            for (int off = 32; off > 0; off >>= 1) r += __shfl_xor(r, off, 64);
            if (d == 0) out[(size_t)b * 400 + (o - 100)] = r;
        }
    }
    __syncthreads();
    #pragma unroll
    for (int n = 0; n < 100; ++n) hr[n] = hs[n][d];
    __syncthreads();

    for (int oi = 0; oi < 25; ++oi) {
        const int o = o0 + oi;
        const float* __restrict__ wrow = w2 + (size_t)o * 4000;
        float s = b2[o];
        for (int m = 0; m < 40; ++m) {
            const float* __restrict__ wm = wrow + m * 100;
            float a0 = 0.f, a1 = 0.f, a2 = 0.f, a3 = 0.f;
            #pragma unroll
            for (int n = 0; n < 100; n += 4) {
                a0 = fmaf(wm[n + 0], hr[n + 0], a0);
                a1 = fmaf(wm[n + 1], hr[n + 1], a1);
                a2 = fmaf(wm[n + 2], hr[n + 2], a2);
                a3 = fmaf(wm[n + 3], hr[n + 3], a3);
            }
            s = fmaf(xs[m][d], (a0 + a1) + (a2 + a3), s);
        }
        s = fmaxf(s, 0.f);
        if (o < 100) hs[o][d] = s;
        else {
            float r = s;
            #pragma unroll
            for (int off = 32; off > 0; off >>= 1) r += __shfl_xor(r, off, 64);
            if (d == 0) out[(size_t)b * 400 + 100 + (o - 100)] = r;
        }
    }
    __syncthreads();
    #pragma unroll
    for (int n = 0; n < 100; ++n) hr[n] = hs[n][d];

    for (int oi = 0; oi < 25; ++oi) {
        const int o = o0 + oi;
        const float* __restrict__ wrow = w3 + (size_t)o * 4000;
        float s = b3[o];
        for (int m = 0; m < 40; ++m) {
            const float* __restrict__ wm = wrow + m * 100;
            float a0 = 0.f, a1 = 0.f, a2 = 0.f, a3 = 0.f;
            #pragma unroll
            for (int n = 0; n < 100; n += 4) {
                a0 = fmaf(wm[n + 0], hr[n + 0], a0);
                a1 = fmaf(wm[n + 1], hr[n + 1], a1);
                a2 = fmaf(wm[n + 2], hr[n + 2], a2);
                a3 = fmaf(wm[n + 3], hr[n + 3], a3);
            }
            s = fmaf(xs[m][d], (a0 + a1) + (a2 + a3), s);
        }
        s = fmaxf(s, 0.f);
        float r = s;
        #pragma unroll
        for (int off = 32; off > 0; off >>= 1) r += __shfl_xor(r, off, 64);
        if (d == 0) out[(size_t)b * 400 + 200 + o] = r;
    }
}

extern "C" void kernel_launch(void* const* d_in, const int* in_sizes, int n_in,
                              void* d_out, int out_size, void* d_ws, size_t ws_size,
                              hipStream_t stream) {
    const float* x  = (const float*)d_in[0];
    const float* w1 = (const float*)d_in[1];
    const float* b1 = (const float*)d_in[2];
    const float* w2 = (const float*)d_in[3];
    const float* b2 = (const float*)d_in[4];
    const float* w3 = (const float*)d_in[5];
    const float* b3 = (const float*)d_in[6];
    float* out = (float*)d_out;

    if (ws_size >= 249600u * 16u) {
        uint4* wp = (uint4*)d_ws;
        convert_pack<<<dim3(975), dim3(256), 0, stream>>>(w1, w2, w3, wp);
        fused_mfma<<<dim3(256), dim3(512), 0, stream>>>(
            x, (const bf16x8*)wp, b1, b2, b3, out);
    } else {
        fused_bilinear_kernel<<<dim3(512), dim3(512), 0, stream>>>(
            x, w1, b1, w2, b2, w3, b3, out);
    }
}

// Round 4
// 227.350 us; speedup vs baseline: 15.5609x; 1.0372x over previous
//
#include <hip/hip_runtime.h>
#include <hip/hip_bf16.h>

// ============================================================================
// B=512, M=40, D=64. Three bilinear layers (200 outputs each):
//   out[o,d] = relu(bias[o] + sum_c W[o,c]*U[c,d]), U[(m,n),d] = x[m,d]*h[n,d]
// Per b: GEMM C[208,64] = W[208,K] x U[K,64] in bf16, K = 1600/4000/4000.
// Block = 2 b's (N=128), grid 256 (1/CU). 8 waves = 4(m)x2(b).
// W repacked frag-contiguous (prepass). U slab per kstep: [d][16 dwords]
// (64B rows) with XOR position permutation pos(j,d)=2*((j>>1)^((d>>1)&7))+(j&1)
// -> build = 1 ds_write_b64/bb (bank-optimal), consume = 8 ds_read_b64
// (bank-optimal) instead of 16 ds_read_b32. LDS pipe ~450 cyc/kstep < MFMA 504.
// ============================================================================

typedef float f32x4 __attribute__((ext_vector_type(4)));
typedef short bf16x8 __attribute__((ext_vector_type(8)));
typedef unsigned int uint;

#define NTILES 13
#define XS_STR 44     // bf16; 88B rows -> 8B-aligned uint2 reads, 4-lane/bank-pair
#define HS_STR 108    // bf16; 216B rows -> 8B-aligned, bank-optimal uniform reads

struct LDSState {
    __hip_bfloat16 xs[2][64][XS_STR];     // [bb][d][m]
    __hip_bfloat16 hs[2][2][64][HS_STR];  // [pp][bb][d][n]
    uint U[4][2][64][16];                 // [slab][bb][d][pos] 64B rows, XOR-permuted
};

static __device__ __forceinline__ float bflo(uint u) {
    uint v = u << 16; return __builtin_bit_cast(float, v);
}
static __device__ __forceinline__ float bfhi(uint u) {
    uint v = u & 0xffff0000u; return __builtin_bit_cast(float, v);
}
static __device__ __forceinline__ uint pk_bf16(float a, float b) {
    uint r; asm("v_cvt_pk_bf16_f32 %0, %1, %2" : "=v"(r) : "v"(a), "v"(b));
    return r;
}

template<int DIV, int KTOT, int HASH, int ROWLO, int ROWOFF, int HSTR>
__device__ __forceinline__ void layer_pass(
    LDSState* L, const bf16x8* __restrict__ wpk, const float* __restrict__ bias,
    const __hip_bfloat16* __restrict__ h0, const __hip_bfloat16* __restrict__ h1,
    int dstpp, float* outb0, float* outb1, int tid)
{
    const int lane = tid & 63;
    const int wv = tid >> 6, wm = wv >> 1, wn = wv & 1;
    const int q = lane >> 4, lr = lane & 15, d = lane;
    const int hd = (lane >> 1) & 7;          // row-hash for XOR position perm
    const int nk = KTOT / 32, NS = nk;

    bool mvalid[4];
    const bf16x8* pA[4];
    #pragma unroll
    for (int mi = 0; mi < 4; ++mi) {
        const int mt = 4 * mi + wm;
        mvalid[mi] = (mt < NTILES);
        pA[mi] = wpk + ((size_t)mt * NS * 64 + lane);
    }

    // loop-invariant read offsets (dwords within a U [64][16] slab)
    int offA[4], offB[4];
    #pragma unroll
    for (int nj = 0; nj < 4; ++nj) {
        offA[nj] = (16 * nj + lr) * 16 + 2 * ((2 * q)     ^ hd);
        offB[nj] = (16 * nj + lr) * 16 + 2 * ((2 * q + 1) ^ hd);
    }
    const int uwr = 2 * (wv ^ hd);           // build write position (dwords)

    f32x4 acc[4][4];
    #pragma unroll
    for (int mi = 0; mi < 4; ++mi)
        #pragma unroll
        for (int nj = 0; nj < 4; ++nj)
            acc[mi][nj] = {0.f, 0.f, 0.f, 0.f};

    // build: wave wv computes k-local 4wv..4wv+3 (logical dwords 2wv,2wv+1)
    auto build = [&](int k) {
        if (k >= nk) return;
        const int c0 = k * 32 + 4 * wv;
        const int m  = c0 / DIV;
        const int n0 = c0 % DIV;             // multiple of 4, never straddles
        const int slab = k & 3;
        #pragma unroll
        for (int bb = 0; bb < 2; ++bb) {
            const __hip_bfloat16* hb = bb ? h1 : h0;
            float xf = __bfloat162float(L->xs[bb][d][m]);
            uint2 h03 = *(const uint2*)(hb + (size_t)d * HSTR + n0);
            uint2 w;
            w.x = pk_bf16(xf * bflo(h03.x), xf * bfhi(h03.x));
            w.y = pk_bf16(xf * bflo(h03.y), xf * bfhi(h03.y));
            *(uint2*)(&L->U[slab][bb][d][0] + uwr) = w;
        }
    };

    auto consume = [&](int s, bf16x8* a) {
        const uint* ub = &L->U[s & 3][wn][0][0];
        bf16x8 bv[4];
        #pragma unroll
        for (int nj = 0; nj < 4; ++nj) {
            union { uint2 u2[2]; bf16x8 v; } t;
            t.u2[0] = *(const uint2*)(ub + offA[nj]);   // k 8q..8q+3
            t.u2[1] = *(const uint2*)(ub + offB[nj]);   // k 8q+4..8q+7
            bv[nj] = t.v;
        }
        __builtin_amdgcn_s_setprio(1);
        #pragma unroll
        for (int mi = 0; mi < 4; ++mi) {
            if (!mvalid[mi]) continue;       // wave-uniform
            #pragma unroll
            for (int nj = 0; nj < 4; ++nj)
                acc[mi][nj] = __builtin_amdgcn_mfma_f32_16x16x32_bf16(
                    a[mi], bv[nj], acc[mi][nj], 0, 0, 0);
        }
        __builtin_amdgcn_s_setprio(0);
    };

    bf16x8 aC[4], aC2[4], aN[4], aN2[4];
    #pragma unroll
    for (int mi = 0; mi < 4; ++mi) if (mvalid[mi]) {
        aC[mi]  = pA[mi][0];
        aC2[mi] = pA[mi][64];
    }
    build(0); build(1);
    __syncthreads();

    for (int s = 0; s < nk; s += 2) {
        if (s + 2 < nk) {
            #pragma unroll
            for (int mi = 0; mi < 4; ++mi) if (mvalid[mi]) aN[mi] = pA[mi][(s + 2) * 64];
        }
        if (s + 3 < nk) {
            #pragma unroll
            for (int mi = 0; mi < 4; ++mi) if (mvalid[mi]) aN2[mi] = pA[mi][(s + 3) * 64];
        }
        build(s + 2); build(s + 3);          // writes slabs (s+2)&3,(s+3)&3
        consume(s, aC);                      // reads slabs s&3,(s+1)&3
        if (s + 1 < nk) consume(s + 1, aC2);
        __syncthreads();
        #pragma unroll
        for (int mi = 0; mi < 4; ++mi) { aC[mi] = aN[mi]; aC2[mi] = aN2[mi]; }
    }

    // epilogue: C/D layout row = 4q+reg, col = lr (m89-verified)
    float* outp = wn ? outb1 : outb0;
    #pragma unroll
    for (int mi = 0; mi < 4; ++mi) {
        if (!mvalid[mi]) continue;
        const int mt = 4 * mi + wm;
        #pragma unroll
        for (int reg = 0; reg < 4; ++reg) {
            const int o = 16 * mt + 4 * q + reg;
            if (o < 200) {
                const float bs = bias[o];
                float r0 = fmaxf(acc[mi][0][reg] + bs, 0.f);
                float r1 = fmaxf(acc[mi][1][reg] + bs, 0.f);
                float r2 = fmaxf(acc[mi][2][reg] + bs, 0.f);
                float r3 = fmaxf(acc[mi][3][reg] + bs, 0.f);
                if (HASH && o < 100) {
                    L->hs[dstpp][wn][ 0 + lr][o] = __float2bfloat16(r0);
                    L->hs[dstpp][wn][16 + lr][o] = __float2bfloat16(r1);
                    L->hs[dstpp][wn][32 + lr][o] = __float2bfloat16(r2);
                    L->hs[dstpp][wn][48 + lr][o] = __float2bfloat16(r3);
                }
                if (o >= ROWLO) {
                    float sv = (r0 + r1) + (r2 + r3);
                    sv += __shfl_xor(sv, 1, 64);
                    sv += __shfl_xor(sv, 2, 64);
                    sv += __shfl_xor(sv, 4, 64);
                    sv += __shfl_xor(sv, 8, 64);
                    if (lr == 0) outp[ROWOFF + (o - ROWLO)] = sv;
                }
            }
        }
    }
    __syncthreads();
}

__global__ __launch_bounds__(512, 2)
void fused_mfma(const float* __restrict__ x,
                const bf16x8* __restrict__ wpk,
                const float* __restrict__ b1, const float* __restrict__ b2,
                const float* __restrict__ b3, float* __restrict__ out) {
    __shared__ LDSState L;
    const int tid = threadIdx.x;
    const int bi  = blockIdx.x;

    // stage x (2 b's), fp32 -> bf16, transposed to [d][m]
    for (int i = tid; i < 5120; i += 512) {
        int bb = (i >= 2560) ? 1 : 0;
        int r  = i - bb * 2560;
        float v = x[(size_t)(2 * bi + bb) * 2560 + r];
        L.xs[bb][r & 63][r >> 6] = __float2bfloat16(v);
    }
    __syncthreads();

    float* outb0 = out + (size_t)(2 * bi + 0) * 400;
    float* outb1 = out + (size_t)(2 * bi + 1) * 400;

    const bf16x8* w1p = wpk;             // 13*50*64  = 41600 frags
    const bf16x8* w2p = wpk + 41600;     // 13*125*64 = 104000
    const bf16x8* w3p = wpk + 145600;

    layer_pass< 40, 1600, 1, 100,   0, XS_STR>(&L, w1p, b1, &L.xs[0][0][0],
                                       &L.xs[1][0][0], 0, outb0, outb1, tid);
    layer_pass<100, 4000, 1, 100, 100, HS_STR>(&L, w2p, b2, &L.hs[0][0][0][0],
                                       &L.hs[0][1][0][0], 1, outb0, outb1, tid);
    layer_pass<100, 4000, 0,   0, 200, HS_STR>(&L, w3p, b3, &L.hs[1][0][0][0],
                                       &L.hs[1][1][0][0], 0, outb0, outb1, tid);
}

// ---------------------------------------------------------------------------
// Prepass: repack W fp32 -> bf16 frag-contiguous. Element c = one lane's
// bf16x8: c = layerbase + (mt*NS + s)*64 + lane, holding
// W[16*mt + (lane&15), 32*s + 8*(lane>>4) .. +8]  (rows >= 200 zero).
// ---------------------------------------------------------------------------
__global__ void convert_pack(const float* __restrict__ w1, const float* __restrict__ w2,
                             const float* __restrict__ w3, uint4* __restrict__ outp) {
    int c = blockIdx.x * 256 + threadIdx.x;
    if (c >= 249600) return;
    const float* src; int K, base;
    if (c < 41600)       { src = w1; K = 1600; base = c; }
    else if (c < 145600) { src = w2; K = 4000; base = c - 41600; }
    else                 { src = w3; K = 4000; base = c - 145600; }
    const int NS   = K / 32;
    const int lane = base & 63;
    const int t    = base >> 6;
    const int mt   = t / NS;
    const int s    = t - mt * NS;
    const int row  = 16 * mt + (lane & 15);
    const int k0   = 32 * s + 8 * (lane >> 4);
    uint o[4];
    if (row < 200) {
        const float* p = src + (size_t)row * K + k0;
        #pragma unroll
        for (int j = 0; j < 4; ++j) {
            __hip_bfloat16 lo = __float2bfloat16(p[2 * j]);
            __hip_bfloat16 hi = __float2bfloat16(p[2 * j + 1]);
            o[j] = (uint)__builtin_bit_cast(unsigned short, lo)
                 | ((uint)__builtin_bit_cast(unsigned short, hi) << 16);
        }
    } else {
        #pragma unroll
        for (int j = 0; j < 4; ++j) o[j] = 0u;
    }
    uint4 v; v.x = o[0]; v.y = o[1]; v.z = o[2]; v.w = o[3];
    outp[c] = v;
}

// ---------------------------------------------------------------------------
// Fallback (round-1 fp32 kernel) if ws too small.
// ---------------------------------------------------------------------------
__global__ __launch_bounds__(512, 1)
void fused_bilinear_kernel(const float* __restrict__ x,
                           const float* __restrict__ w1, const float* __restrict__ b1,
                           const float* __restrict__ w2, const float* __restrict__ b2,
                           const float* __restrict__ w3, const float* __restrict__ b3,
                           float* __restrict__ out) {
    const int b   = blockIdx.x;
    const int tid = threadIdx.x;
    const int d   = tid & 63;
    const int wv  = tid >> 6;

    __shared__ float xs[40][64];
    __shared__ float hs[100][64];

    const float* xb = x + (size_t)b * 40 * 64;
    for (int i = tid; i < 40 * 64; i += 512) ((float*)xs)[i] = xb[i];
    __syncthreads();

    float xr[40];
    #pragma unroll
    for (int m = 0; m < 40; ++m) xr[m] = xs[m][d];
    float hr[100];
    const int o0 = __builtin_amdgcn_readfirstlane(wv * 25);

    for (int oi = 0; oi < 25; ++oi) {
        const int o = o0 + oi;
        const float* __restrict__ wrow = w1 + (size_t)o * 1600;
        float s = b1[o];
        for (int m = 0; m < 40; ++m) {
            const float* __restrict__ wm = wrow + m * 40;
            float a0 = 0.f, a1 = 0.f, a2 = 0.f, a3 = 0.f;
            #pragma unroll
            for (int n = 0; n < 40; n += 4) {
                a0 = fmaf(wm[n + 0], xr[n + 0], a0);
                a1 = fmaf(wm[n + 1], xr[n + 1], a1);
                a2 = fmaf(wm[n + 2], xr[n + 2], a2);
                a3 = fmaf(wm[n + 3], xr[n + 3], a3);
            }
            s = fmaf(xs[m][d], (a0 + a1) + (a2 + a3), s);
        }
        s = fmaxf(s, 0.f);
        if (o < 100) hs[o][d] = s;
        else {
            float r = s;
            #pragma unroll
            for (int off = 32; off > 0; off >>= 1) r += __shfl_xor(r, off, 64);
            if (d == 0) out[(size_t)b * 400 + (o - 100)] = r;
        }
    }
    __syncthreads();
    #pragma unroll
    for (int n = 0; n < 100; ++n) hr[n] = hs[n][d];
    __syncthreads();

    for (int oi = 0; oi < 25; ++oi) {
        const int o = o0 + oi;
        const float* __restrict__ wrow = w2 + (size_t)o * 4000;
        float s = b2[o];
        for (int m = 0; m < 40; ++m) {
            const float* __restrict__ wm = wrow + m * 100;
            float a0 = 0.f, a1 = 0.f, a2 = 0.f, a3 = 0.f;
            #pragma unroll
            for (int n = 0; n < 100; n += 4) {
                a0 = fmaf(wm[n + 0], hr[n + 0], a0);
                a1 = fmaf(wm[n + 1], hr[n + 1], a1);
                a2 = fmaf(wm[n + 2], hr[n + 2], a2);
                a3 = fmaf(wm[n + 3], hr[n + 3], a3);
            }
            s = fmaf(xs[m][d], (a0 + a1) + (a2 + a3), s);
        }
        s = fmaxf(s, 0.f);
        if (o < 100) hs[o][d] = s;
        else {
            float r = s;
            #pragma unroll
            for (int off = 32; off > 0; off >>= 1) r += __shfl_xor(r, off, 64);
            if (d == 0) out[(size_t)b * 400 + 100 + (o - 100)] = r;
        }
    }
    __syncthreads();
    #pragma unroll
    for (int n = 0; n < 100; ++n) hr[n] = hs[n][d];

    for (int oi = 0; oi < 25; ++oi) {
        const int o = o0 + oi;
        const float* __restrict__ wrow = w3 + (size_t)o * 4000;
        float s = b3[o];
        for (int m = 0; m < 40; ++m) {
            const float* __restrict__ wm = wrow + m * 100;
            float a0 = 0.f, a1 = 0.f, a2 = 0.f, a3 = 0.f;
            #pragma unroll
            for (int n = 0; n < 100; n += 4) {
                a0 = fmaf(wm[n + 0], hr[n + 0], a0);
                a1 = fmaf(wm[n + 1], hr[n + 1], a1);
                a2 = fmaf(wm[n + 2], hr[n + 2], a2);
                a3 = fmaf(wm[n + 3], hr[n + 3], a3);
            }
            s = fmaf(xs[m][d], (a0 + a1) + (a2 + a3), s);
        }
        s = fmaxf(s, 0.f);
        float r = s;
        #pragma unroll
        for (int off = 32; off > 0; off >>= 1) r += __shfl_xor(r, off, 64);
        if (d == 0) out[(size_t)b * 400 + 200 + o] = r;
    }
}

extern "C" void kernel_launch(void* const* d_in, const int* in_sizes, int n_in,
                              void* d_out, int out_size, void* d_ws, size_t ws_size,
                              hipStream_t stream) {
    const float* x  = (const float*)d_in[0];
    const float* w1 = (const float*)d_in[1];
    const float* b1 = (const float*)d_in[2];
    const float* w2 = (const float*)d_in[3];
    const float* b2 = (const float*)d_in[4];
    const float* w3 = (const float*)d_in[5];
    const float* b3 = (const float*)d_in[6];
    float* out = (float*)d_out;

    if (ws_size >= 249600u * 16u) {
        uint4* wp = (uint4*)d_ws;
        convert_pack<<<dim3(975), dim3(256), 0, stream>>>(w1, w2, w3, wp);
        fused_mfma<<<dim3(256), dim3(512), 0, stream>>>(
            x, (const bf16x8*)wp, b1, b2, b3, out);
    } else {
        fused_bilinear_kernel<<<dim3(512), dim3(512), 0, stream>>>(
            x, w1, b1, w2, b2, w3, b3, out);
    }
}

// Round 5
// 162.814 us; speedup vs baseline: 21.7290x; 1.3964x over previous
//
#include <hip/hip_runtime.h>
#include <hip/hip_bf16.h>

// ============================================================================
// B=512, M=40, D=64. Three bilinear layers (200 outputs each):
//   out[o,d] = relu(bias[o] + sum_c W[o,c]*U[c,d]), U[(m,n),d] = x[m,d]*h[n,d]
// Per b: GEMM C[208,64] = W[208,K] x U[K,64] bf16, K=1600/4000/4000.
// Block = 2 b's (N=128), grid 256. 8 waves: wv=tid>>6; wm=wv>>1 picks m-tiles
// (wm0: tiles 0-3, wm1: 4-6, wm2: 7-9, wm3: 10-12), wn=wv&1 picks b.
// W repacked frag-contiguous (prepass). U: 4 slabs [d][16dw], XOR pos-perm
// pos = 2*((j>>1)^((d>>1)&7)) + (j&1). Main loop unrolled 4 ksteps -> all
// slab indices compile-time (LDS addr = base VGPR + immediate). Raw s_barrier
// + lgkmcnt(0) only (A-frag global loads are wave-private -> fly across
// barriers, no vmcnt(0) drain). Frag loads overwrite consumed regs (no moves).
// ============================================================================

typedef float f32x4 __attribute__((ext_vector_type(4)));
typedef short bf16x8 __attribute__((ext_vector_type(8)));
typedef unsigned int uint;

#define XS_STR 44     // bf16; 88B rows
#define HS_STR 108    // bf16; 216B rows

struct LDSState {
    __hip_bfloat16 xs[2][64][XS_STR];     // [bb][d][m]
    __hip_bfloat16 hs[2][2][64][HS_STR];  // [pp][bb][d][n]
    uint U[4][2][64][16];                 // [slab][bb][d][pos]
};

static __device__ __forceinline__ float bflo(uint u) {
    uint v = u << 16; return __builtin_bit_cast(float, v);
}
static __device__ __forceinline__ float bfhi(uint u) {
    uint v = u & 0xffff0000u; return __builtin_bit_cast(float, v);
}
static __device__ __forceinline__ uint pk_bf16(float a, float b) {
    uint r; asm("v_cvt_pk_bf16_f32 %0, %1, %2" : "=v"(r) : "v"(a), "v"(b));
    return r;
}

#define PHASE_BAR() do {                                   \
    asm volatile("s_waitcnt lgkmcnt(0)" ::: "memory");     \
    __builtin_amdgcn_sched_barrier(0);                     \
    __builtin_amdgcn_s_barrier();                          \
    __builtin_amdgcn_sched_barrier(0);                     \
} while (0)

template<int DIV, int NK, int HASH, int ROWLO, int ROWOFF, int HSTR, int A>
__device__ __forceinline__ void layer_core(
    LDSState* L, const bf16x8* __restrict__ wpk, const float* __restrict__ bias,
    const __hip_bfloat16* __restrict__ h0, const __hip_bfloat16* __restrict__ h1,
    int dstpp, float* outb0, float* outb1, int tid, int mt0)
{
    const int lane = tid & 63;
    const int wv = tid >> 6, wn = wv & 1;
    const int q = lane >> 4, lr = lane & 15, d = lane;

    // consume read bases (per-lane, fixed; slab/nj become immediates)
    const int hdr = (lr >> 1) & 7;
    const uint* ub  = &L->U[0][0][0][0] + wn * 1024;
    const uint* roA = ub + (lr * 16 + 2 * ((2 * q) ^ hdr));
    const uint* roB = ub + (lr * 16 + 2 * ((2 * q + 1) ^ hdr));

    // build write base (wave wv owns k-local slots 4wv..4wv+3 = dword pair wv)
    const int hdw = (d >> 1) & 7;
    uint* wb = &L->U[0][0][d][0] + 2 * (wv ^ hdw);

    const __hip_bfloat16* xb0 = &L->xs[0][d][0];
    const __hip_bfloat16* xb1 = &L->xs[1][d][0];
    const __hip_bfloat16* hb0 = h0 + d * HSTR;
    const __hip_bfloat16* hb1 = h1 + d * HSTR;

    f32x4 acc[A][4];
    #pragma unroll
    for (int mi = 0; mi < A; ++mi)
        #pragma unroll
        for (int nj = 0; nj < 4; ++nj)
            acc[mi][nj] = {0.f, 0.f, 0.f, 0.f};

    // build state: (bm, bn) = c0 decomposition for kstep bk; advance by 32/call
    int bm = (4 * wv) / DIV;
    int bn = (4 * wv) % DIV;
    int bk = 0;

    auto build = [&](int slab) {
        if (bk < NK) {
            float xf0 = __bfloat162float(xb0[bm]);
            float xf1 = __bfloat162float(xb1[bm]);
            uint2 ha = *(const uint2*)(hb0 + bn);
            uint2 hc = *(const uint2*)(hb1 + bn);
            uint2 w0, w1;
            w0.x = pk_bf16(xf0 * bflo(ha.x), xf0 * bfhi(ha.x));
            w0.y = pk_bf16(xf0 * bflo(ha.y), xf0 * bfhi(ha.y));
            w1.x = pk_bf16(xf1 * bflo(hc.x), xf1 * bfhi(hc.x));
            w1.y = pk_bf16(xf1 * bflo(hc.y), xf1 * bfhi(hc.y));
            *(uint2*)(wb + slab * 2048)        = w0;
            *(uint2*)(wb + slab * 2048 + 1024) = w1;
            bn += 32;
            if (bn >= DIV) { bn -= DIV; bm += 1; }
            ++bk;
        }
    };

    auto consume = [&](int slab, bf16x8* a) {
        bf16x8 bv[4];
        #pragma unroll
        for (int nj = 0; nj < 4; ++nj) {
            union { uint2 u2[2]; bf16x8 v; } t;
            t.u2[0] = *(const uint2*)(roA + slab * 2048 + nj * 256);
            t.u2[1] = *(const uint2*)(roB + slab * 2048 + nj * 256);
            bv[nj] = t.v;
        }
        #pragma unroll
        for (int mi = 0; mi < A; ++mi)
            #pragma unroll
            for (int nj = 0; nj < 4; ++nj)
                acc[mi][nj] = __builtin_amdgcn_mfma_f32_16x16x32_bf16(
                    a[mi], bv[nj], acc[mi][nj], 0, 0, 0);
    };

    const bf16x8* pw = wpk + (size_t)mt0 * NK * 64 + lane;
    auto loadf = [&](bf16x8* f, int s) {
        if (s < NK) {
            #pragma unroll
            for (int mi = 0; mi < A; ++mi)
                f[mi] = pw[(size_t)mi * NK * 64 + s * 64];
        }
    };

    bf16x8 f0[A], f1[A], f2[A], f3[A];
    build(0); build(1);                 // ksteps 0,1 -> slabs 0,1
    loadf(f0, 0); loadf(f1, 1); loadf(f2, 2); loadf(f3, 3);
    __syncthreads();

    int s = 0;
    #pragma unroll 1
    for (; s + 4 <= NK; s += 4) {
        // sub-phase A: consume s,s+1 (slabs 0,1); build s+2,s+3 (slabs 2,3)
        consume(0, f0);
        loadf(f0, s + 4);
        consume(1, f1);
        loadf(f1, s + 5);
        build(2); build(3);
        PHASE_BAR();
        // sub-phase B: consume s+2,s+3 (slabs 2,3); build s+4,s+5 (slabs 0,1)
        consume(2, f2);
        loadf(f2, s + 6);
        consume(3, f3);
        loadf(f3, s + 7);
        build(0); build(1);
        PHASE_BAR();
    }
    // tail (NK=50 -> 2 ksteps, slabs 0,1; NK=125 -> 1 kstep, slab 0)
    if (NK % 4 >= 1) consume(0, f0);
    if (NK % 4 >= 2) consume(1, f1);
    if (NK % 4 >= 3) consume(2, f2);

    // epilogue: C/D layout row = 4q+reg, col = lr (m89-verified)
    float* outp = wn ? outb1 : outb0;
    #pragma unroll
    for (int mi = 0; mi < A; ++mi) {
        const int mt = mt0 + mi;
        #pragma unroll
        for (int reg = 0; reg < 4; ++reg) {
            const int o = 16 * mt + 4 * q + reg;
            if (o < 200) {
                const float bs = bias[o];
                float r0 = fmaxf(acc[mi][0][reg] + bs, 0.f);
                float r1 = fmaxf(acc[mi][1][reg] + bs, 0.f);
                float r2 = fmaxf(acc[mi][2][reg] + bs, 0.f);
                float r3 = fmaxf(acc[mi][3][reg] + bs, 0.f);
                if (HASH && o < 100) {
                    L->hs[dstpp][wn][ 0 + lr][o] = __float2bfloat16(r0);
                    L->hs[dstpp][wn][16 + lr][o] = __float2bfloat16(r1);
                    L->hs[dstpp][wn][32 + lr][o] = __float2bfloat16(r2);
                    L->hs[dstpp][wn][48 + lr][o] = __float2bfloat16(r3);
                }
                if (o >= ROWLO) {
                    float sv = (r0 + r1) + (r2 + r3);
                    sv += __shfl_xor(sv, 1, 64);
                    sv += __shfl_xor(sv, 2, 64);
                    sv += __shfl_xor(sv, 4, 64);
                    sv += __shfl_xor(sv, 8, 64);
                    if (lr == 0) outp[ROWOFF + (o - ROWLO)] = sv;
                }
            }
        }
    }
    __syncthreads();
}

template<int A>
__device__ __forceinline__ void run_layers(
    LDSState* L, const bf16x8* w1p, const bf16x8* w2p, const bf16x8* w3p,
    const float* b1, const float* b2, const float* b3,
    float* outb0, float* outb1, int tid, int mt0)
{
    layer_core< 40,  50, 1, 100,   0, XS_STR, A>(L, w1p, b1,
        &L->xs[0][0][0], &L->xs[1][0][0], 0, outb0, outb1, tid, mt0);
    layer_core<100, 125, 1, 100, 100, HS_STR, A>(L, w2p, b2,
        &L->hs[0][0][0][0], &L->hs[0][1][0][0], 1, outb0, outb1, tid, mt0);
    layer_core<100, 125, 0,   0, 200, HS_STR, A>(L, w3p, b3,
        &L->hs[1][0][0][0], &L->hs[1][1][0][0], 0, outb0, outb1, tid, mt0);
}

__global__ __launch_bounds__(512, 2)
void fused_mfma(const float* __restrict__ x,
                const bf16x8* __restrict__ wpk,
                const float* __restrict__ b1, const float* __restrict__ b2,
                const float* __restrict__ b3, float* __restrict__ out) {
    __shared__ LDSState L;
    const int tid = threadIdx.x;
    const int bi  = blockIdx.x;

    // stage x (2 b's), fp32 -> bf16, transposed to [d][m]
    for (int i = tid; i < 5120; i += 512) {
        int bb = (i >= 2560) ? 1 : 0;
        int r  = i - bb * 2560;
        float v = x[(size_t)(2 * bi + bb) * 2560 + r];
        L.xs[bb][r & 63][r >> 6] = __float2bfloat16(v);
    }
    __syncthreads();

    float* outb0 = out + (size_t)(2 * bi + 0) * 400;
    float* outb1 = out + (size_t)(2 * bi + 1) * 400;

    const bf16x8* w1p = wpk;             // 13*50*64  frags
    const bf16x8* w2p = wpk + 41600;     // 13*125*64
    const bf16x8* w3p = wpk + 145600;

    const int wm = tid >> 7;             // wave-pair id 0..3
    if (wm == 0)
        run_layers<4>(&L, w1p, w2p, w3p, b1, b2, b3, outb0, outb1, tid, 0);
    else
        run_layers<3>(&L, w1p, w2p, w3p, b1, b2, b3, outb0, outb1, tid,
                      3 * wm + 1);
}

// ---------------------------------------------------------------------------
// Prepass: repack W fp32 -> bf16 frag-contiguous. Element c = one lane's
// bf16x8: c = layerbase + (mt*NS + s)*64 + lane, holding
// W[16*mt + (lane&15), 32*s + 8*(lane>>4) .. +8]  (rows >= 200 zero).
// ---------------------------------------------------------------------------
__global__ void convert_pack(const float* __restrict__ w1, const float* __restrict__ w2,
                             const float* __restrict__ w3, uint4* __restrict__ outp) {
    int c = blockIdx.x * 256 + threadIdx.x;
    if (c >= 249600) return;
    const float* src; int K, base;
    if (c < 41600)       { src = w1; K = 1600; base = c; }
    else if (c < 145600) { src = w2; K = 4000; base = c - 41600; }
    else                 { src = w3; K = 4000; base = c - 145600; }
    const int NS   = K / 32;
    const int lane = base & 63;
    const int t    = base >> 6;
    const int mt   = t / NS;
    const int s    = t - mt * NS;
    const int row  = 16 * mt + (lane & 15);
    const int k0   = 32 * s + 8 * (lane >> 4);
    uint o[4];
    if (row < 200) {
        const float* p = src + (size_t)row * K + k0;
        #pragma unroll
        for (int j = 0; j < 4; ++j) {
            __hip_bfloat16 lo = __float2bfloat16(p[2 * j]);
            __hip_bfloat16 hi = __float2bfloat16(p[2 * j + 1]);
            o[j] = (uint)__builtin_bit_cast(unsigned short, lo)
                 | ((uint)__builtin_bit_cast(unsigned short, hi) << 16);
        }
    } else {
        #pragma unroll
        for (int j = 0; j < 4; ++j) o[j] = 0u;
    }
    uint4 v; v.x = o[0]; v.y = o[1]; v.z = o[2]; v.w = o[3];
    outp[c] = v;
}

// ---------------------------------------------------------------------------
// Fallback (fp32 VALU kernel) if ws too small.
// ---------------------------------------------------------------------------
__global__ __launch_bounds__(512, 1)
void fused_bilinear_kernel(const float* __restrict__ x,
                           const float* __restrict__ w1, const float* __restrict__ b1,
                           const float* __restrict__ w2, const float* __restrict__ b2,
                           const float* __restrict__ w3, const float* __restrict__ b3,
                           float* __restrict__ out) {
    const int b   = blockIdx.x;
    const int tid = threadIdx.x;
    const int d   = tid & 63;
    const int wv  = tid >> 6;

    __shared__ float xs[40][64];
    __shared__ float hs[100][64];

    const float* xb = x + (size_t)b * 40 * 64;
    for (int i = tid; i < 40 * 64; i += 512) ((float*)xs)[i] = xb[i];
    __syncthreads();

    float xr[40];
    #pragma unroll
    for (int m = 0; m < 40; ++m) xr[m] = xs[m][d];
    float hr[100];
    const int o0 = __builtin_amdgcn_readfirstlane(wv * 25);

    for (int oi = 0; oi < 25; ++oi) {
        const int o = o0 + oi;
        const float* __restrict__ wrow = w1 + (size_t)o * 1600;
        float s = b1[o];
        for (int m = 0; m < 40; ++m) {
            const float* __restrict__ wm = wrow + m * 40;
            float a0 = 0.f, a1 = 0.f, a2 = 0.f, a3 = 0.f;
            #pragma unroll
            for (int n = 0; n < 40; n += 4) {
                a0 = fmaf(wm[n + 0], xr[n + 0], a0);
                a1 = fmaf(wm[n + 1], xr[n + 1], a1);
                a2 = fmaf(wm[n + 2], xr[n + 2], a2);
                a3 = fmaf(wm[n + 3], xr[n + 3], a3);
            }
            s = fmaf(xs[m][d], (a0 + a1) + (a2 + a3), s);
        }
        s = fmaxf(s, 0.f);
        if (o < 100) hs[o][d] = s;
        else {
            float r = s;
            #pragma unroll
            for (int off = 32; off > 0; off >>= 1) r += __shfl_xor(r, off, 64);
            if (d == 0) out[(size_t)b * 400 + (o - 100)] = r;
        }
    }
    __syncthreads();
    #pragma unroll
    for (int n = 0; n < 100; ++n) hr[n] = hs[n][d];
    __syncthreads();

    for (int oi = 0; oi < 25; ++oi) {
        const int o = o0 + oi;
        const float* __restrict__ wrow = w2 + (size_t)o * 4000;
        float s = b2[o];
        for (int m = 0; m < 40; ++m) {
            const float* __restrict__ wm = wrow + m * 100;
            float a0 = 0.f, a1 = 0.f, a2 = 0.f, a3 = 0.f;
            #pragma unroll
            for (int n = 0; n < 100; n += 4) {
                a0 = fmaf(wm[n + 0], hr[n + 0], a0);
                a1 = fmaf(wm[n + 1], hr[n + 1], a1);
                a2 = fmaf(wm[n + 2], hr[n + 2], a2);
                a3 = fmaf(wm[n + 3], hr[n + 3], a3);
            }
            s = fmaf(xs[m][d], (a0 + a1) + (a2 + a3), s);
        }
        s = fmaxf(s, 0.f);
        if (o < 100) hs[o][d] = s;
        else {
            float r = s;
            #pragma unroll
            for (int off = 32; off > 0; off >>= 1) r += __shfl_xor(r, off, 64);
            if (d == 0) out[(size_t)b * 400 + 100 + (o - 100)] = r;
        }
    }
    __syncthreads();
    #pragma unroll
    for (int n = 0; n < 100; ++n) hr[n] = hs[n][d];

    for (int oi = 0; oi < 25; ++oi) {
        const int o = o0 + oi;
        const float* __restrict__ wrow = w3 + (size_t)o * 4000;
        float s = b3[o];
        for (int m = 0; m < 40; ++m) {
            const float* __restrict__ wm = wrow + m * 100;
            float a0 = 0.f, a1 = 0.f, a2 = 0.f, a3 = 0.f;
            #pragma unroll
            for (int n = 0; n < 100; n += 4) {
                a0 = fmaf(wm[n + 0], hr[n + 0], a0);
                a1 = fmaf(wm[n + 1], hr[n + 1], a1);
                a2 = fmaf(wm[n + 2], hr[n + 2], a2);
                a3 = fmaf(wm[n + 3], hr[n + 3], a3);
            }
            s = fmaf(xs[m][d], (a0 + a1) + (a2 + a3), s);
        }
        s = fmaxf(s, 0.f);
        float r = s;
        #pragma unroll
        for (int off = 32; off > 0; off >>= 1) r += __shfl_xor(r, off, 64);
        if (d == 0) out[(size_t)b * 400 + 200 + o] = r;
    }
}

extern "C" void kernel_launch(void* const* d_in, const int* in_sizes, int n_in,
                              void* d_out, int out_size, void* d_ws, size_t ws_size,
                              hipStream_t stream) {
    const float* x  = (const float*)d_in[0];
    const float* w1 = (const float*)d_in[1];
    const float* b1 = (const float*)d_in[2];
    const float* w2 = (const float*)d_in[3];
    const float* b2 = (const float*)d_in[4];
    const float* w3 = (const float*)d_in[5];
    const float* b3 = (const float*)d_in[6];
    float* out = (float*)d_out;

    if (ws_size >= 249600u * 16u) {
        uint4* wp = (uint4*)d_ws;
        convert_pack<<<dim3(975), dim3(256), 0, stream>>>(w1, w2, w3, wp);
        fused_mfma<<<dim3(256), dim3(512), 0, stream>>>(
            x, (const bf16x8*)wp, b1, b2, b3, out);
    } else {
        fused_bilinear_kernel<<<dim3(512), dim3(512), 0, stream>>>(
            x, w1, b1, w2, b2, w3, b3, out);
    }
}